// Round 2
// baseline (989.332 us; speedup 1.0000x reference)
//
#include <hip/hip_runtime.h>
#include <hip/hip_bf16.h>
#include <stdint.h>

#define NN 50000
#define HF 128
#define KIN 300
#define TILE1K 1024
#define NT_TILES 49   // ceil(50000/1024)

// ---------- bf16 helpers ----------
__device__ __forceinline__ float bf2f(unsigned short u) {
  union { unsigned int i; float f; } c; c.i = ((unsigned int)u) << 16; return c.f;
}
__device__ __forceinline__ unsigned short f2bf(float f) {
  union { float f; unsigned int i; } c; c.f = f;
  unsigned int x = c.i;
  unsigned int lsb = (x >> 16) & 1u;
  x += 0x7fffu + lsb;
  return (unsigned short)(x >> 16);
}

// ---------- runtime dtype detection ----------
// modes[0]: 1 if float inputs are bf16, 0 if fp32
// modes[1]: 1 if edge_index is int64, 0 if int32
__global__ void k_detect(const void* x, const void* ei, int* modes) {
  __shared__ int cnt[2];
  int t = threadIdx.x;
  if (t < 2) cnt[t] = 0;
  __syncthreads();
  if (t < 64) {
    unsigned short u = ((const unsigned short*)x)[2 * t];
    unsigned e = (u >> 7) & 0xFFu;
    bool sane = (u == 0) || (e >= 96u && e <= 136u);
    if (!sane) atomicAdd(&cnt[0], 1);
  } else if (t < 192) {
    int i = t - 64;
    int v = ((const int*)ei)[2 * i + 1];  // high words if int64
    if (v != 0) atomicAdd(&cnt[1], 1);
  }
  __syncthreads();
  if (t == 0) { modes[0] = (cnt[0] == 0) ? 1 : 0; modes[1] = (cnt[1] == 0) ? 1 : 0; }
}

// ---------- convert all weights/biases to fp32 scratch ----------
#define OFF_EMBW 0
#define OFF_EMBB 38400
#define OFF_W0   38528
#define OFF_B0   87680
#define OFF_W1   88064
#define OFF_B1   137216
#define OFF_LIN  137600
#define OFF_LINB 145792
#define N_WF     145856

__global__ void k_convert(const void* ew, const void* eb, const void* w0, const void* b0,
                          const void* w1, const void* b1, const void* lw, const void* lb,
                          const int* __restrict__ modes, float* __restrict__ Wf) {
  int tid = blockIdx.x * blockDim.x + threadIdx.x;
  if (tid >= N_WF) return;
  const void* src; int o = tid;
  if (o < 38400) { src = ew; }
  else if ((o -= 38400) < 128)  { src = eb; }
  else if ((o -= 128) < 49152)  { src = w0; }
  else if ((o -= 49152) < 384)  { src = b0; }
  else if ((o -= 384) < 49152)  { src = w1; }
  else if ((o -= 49152) < 384)  { src = b1; }
  else if ((o -= 384) < 8192)   { src = lw; }
  else { o -= 8192; src = lb; }
  float v = modes[0] ? bf2f(((const unsigned short*)src)[o]) : ((const float*)src)[o];
  Wf[tid] = v;
}

// ---------- degree histogram ----------
__global__ void k_hist(const void* ei, const int* __restrict__ modes,
                       int* __restrict__ deg, int E3, int E) {
  int t = blockIdx.x * blockDim.x + threadIdx.x;
  if (t >= E3) return;
  int r = t / E, i = t - r * E;
  long long j = (long long)r * 2 * E + E + i;  // dst
  int d = modes[1] ? (int)((const long long*)ei)[j] : ((const int*)ei)[j];
  atomicAdd(&deg[r * NN + d], 1);
}

__global__ void k_dis(const int* __restrict__ deg, float* __restrict__ dis) {
  int t = blockIdx.x * blockDim.x + threadIdx.x;
  if (t < 3 * NN) dis[t] = rsqrtf((float)deg[t] + 1.0f);
}

// ---------- CSR build ----------
__global__ __launch_bounds__(256) void k_tilesum(const int* __restrict__ deg, int* __restrict__ tilesum) {
  int b = blockIdx.x;
  int r = b / NT_TILES, tt = b - r * NT_TILES;
  int base = tt * TILE1K + threadIdx.x * 4;
  int s = 0;
#pragma unroll
  for (int j = 0; j < 4; j++) { int i = base + j; if (i < NN) s += deg[r * NN + i]; }
  __shared__ int red[256];
  red[threadIdx.x] = s; __syncthreads();
  for (int st = 128; st > 0; st >>= 1) {
    if (threadIdx.x < st) red[threadIdx.x] += red[threadIdx.x + st];
    __syncthreads();
  }
  if (threadIdx.x == 0) tilesum[b] = red[0];
}

__global__ void k_scantiles(const int* __restrict__ tilesum, int* __restrict__ tileoff,
                            int* __restrict__ rp) {
  __shared__ int s[3 * NT_TILES];
  int t = threadIdx.x;
  if (t < 3 * NT_TILES) s[t] = tilesum[t];
  __syncthreads();
  if (t == 0) {
    for (int r = 0; r < 3; r++) {
      int run = 0;
      for (int i = 0; i < NT_TILES; i++) { int v = s[r * NT_TILES + i]; s[r * NT_TILES + i] = run; run += v; }
      rp[r * (NN + 1) + NN] = run;  // == E
    }
  }
  __syncthreads();
  if (t < 3 * NT_TILES) tileoff[t] = s[t];
}

__global__ __launch_bounds__(256) void k_rowptr(const int* __restrict__ deg, const int* __restrict__ tileoff,
                                                int* __restrict__ rp, int* __restrict__ cursor) {
  int b = blockIdx.x;
  int r = b / NT_TILES, tt = b - r * NT_TILES;
  int tid = threadIdx.x;
  int base = tt * TILE1K + tid * 4;
  int v[4]; int tsum = 0;
#pragma unroll
  for (int j = 0; j < 4; j++) { int i = base + j; v[j] = (i < NN) ? deg[r * NN + i] : 0; tsum += v[j]; }
  int lane = tid & 63;
  int x = tsum;
  for (int off = 1; off < 64; off <<= 1) {
    int y = __shfl_up(x, off);
    if (lane >= off) x += y;
  }
  __shared__ int wsum[4];
  int wv = tid >> 6;
  if (lane == 63) wsum[wv] = x;
  __syncthreads();
  int run = tileoff[b] + (x - tsum);
  for (int k2 = 0; k2 < wv; k2++) run += wsum[k2];
#pragma unroll
  for (int j = 0; j < 4; j++) {
    int i = base + j;
    if (i < NN) { rp[r * (NN + 1) + i] = run; cursor[r * NN + i] = run; }
    run += v[j];
  }
}

__global__ void k_scatter(const void* ei, const int* __restrict__ modes,
                          int* __restrict__ cursor, int* __restrict__ ssrc, int E3, int E) {
  int t = blockIdx.x * blockDim.x + threadIdx.x;
  if (t >= E3) return;
  int r = t / E, i = t - r * E;
  long long jb = (long long)r * 2 * E;
  int s, d;
  if (modes[1]) { const long long* p = (const long long*)ei; s = (int)p[jb + i]; d = (int)p[jb + E + i]; }
  else          { const int* p = (const int*)ei;             s = p[jb + i];      d = p[jb + E + i]; }
  int pos = atomicAdd(&cursor[r * NN + d], 1);
  ssrc[(long long)r * E + pos] = s;
}

// ---------- fp32 tiled GEMM template ----------
template<int BM, int BN, int BK, int TM, int TN, int NT, bool ADUAL, bool RELU, bool BIAS, bool BF16OUT>
__global__ __launch_bounds__(NT)
void k_gemm(const void* __restrict__ A, const float* __restrict__ B,
            const float* __restrict__ bias, void* __restrict__ Cv,
            int M, int N, int K, long long sBz, long long sCz, const int* __restrict__ modes) {
  static_assert(TN == 4, "TN must be 4");
  __shared__ float As[BM][BK + 1];
  __shared__ float Bs[BK][BN];
  const int tid = threadIdx.x;
  const int bm = blockIdx.x * BM;
  const int z = blockIdx.z;
  const int tx = tid % (BN / TN);
  const int ty = tid / (BN / TN);
  const int fmode = ADUAL ? modes[0] : 0;
  const float* Bz = B + (long long)z * sBz;

  float acc[TM][TN];
#pragma unroll
  for (int i = 0; i < TM; i++)
#pragma unroll
    for (int j = 0; j < TN; j++) acc[i][j] = 0.f;

  for (int kt = 0; kt < K; kt += BK) {
    constexpr int AF4 = BM * BK / (4 * NT);
#pragma unroll
    for (int f = 0; f < AF4; f++) {
      int fid = tid + f * NT;
      int row = fid / (BK / 4);
      int g = fid - row * (BK / 4);
      int m = bm + row;
      int k0 = kt + g * 4;
      float v0 = 0.f, v1 = 0.f, v2 = 0.f, v3 = 0.f;
      if (m < M) {
        if (!ADUAL || fmode == 0) {
          const float* Af = (const float*)A;
          long long o = (long long)m * K + k0;
          if (k0 + 3 < K) {
            float4 v = *(const float4*)(Af + o);
            v0 = v.x; v1 = v.y; v2 = v.z; v3 = v.w;
          } else {
            if (k0     < K) v0 = Af[o];
            if (k0 + 1 < K) v1 = Af[o + 1];
            if (k0 + 2 < K) v2 = Af[o + 2];
            if (k0 + 3 < K) v3 = Af[o + 3];
          }
        } else {
          const unsigned short* Ab = (const unsigned short*)A;
          long long o = (long long)m * K + k0;
          if (k0     < K) v0 = bf2f(Ab[o]);
          if (k0 + 1 < K) v1 = bf2f(Ab[o + 1]);
          if (k0 + 2 < K) v2 = bf2f(Ab[o + 2]);
          if (k0 + 3 < K) v3 = bf2f(Ab[o + 3]);
        }
      }
      int kk = k0 - kt;
      As[row][kk] = v0; As[row][kk + 1] = v1; As[row][kk + 2] = v2; As[row][kk + 3] = v3;
    }
    constexpr int BF4 = BK * BN / (4 * NT);
#pragma unroll
    for (int f = 0; f < BF4; f++) {
      int fid = tid + f * NT;
      int row = fid / (BN / 4);
      int c4 = fid - row * (BN / 4);
      int k = kt + row;
      float4 v = make_float4(0.f, 0.f, 0.f, 0.f);
      if (k < K) v = *(const float4*)(Bz + (long long)k * N + c4 * 4);
      *(float4*)&Bs[row][c4 * 4] = v;
    }
    __syncthreads();
#pragma unroll 8
    for (int kk = 0; kk < BK; kk++) {
      float4 bv = *(const float4*)&Bs[kk][tx * TN];
      float b0v = bv.x, b1v = bv.y, b2v = bv.z, b3v = bv.w;
      float a[TM];
#pragma unroll
      for (int i = 0; i < TM; i++) a[i] = As[ty * TM + i][kk];
#pragma unroll
      for (int i = 0; i < TM; i++) {
        acc[i][0] = fmaf(a[i], b0v, acc[i][0]);
        acc[i][1] = fmaf(a[i], b1v, acc[i][1]);
        acc[i][2] = fmaf(a[i], b2v, acc[i][2]);
        acc[i][3] = fmaf(a[i], b3v, acc[i][3]);
      }
    }
    __syncthreads();
  }
#pragma unroll
  for (int i = 0; i < TM; i++) {
    int m = bm + ty * TM + i;
    if (m >= M) continue;
    float o[TN];
#pragma unroll
    for (int j = 0; j < TN; j++) {
      float v = acc[i][j];
      if (BIAS) v += bias[tx * TN + j];
      if (RELU) v = fmaxf(v, 0.f);
      o[j] = v;
    }
    long long co = (long long)z * sCz + (long long)m * N + tx * TN;
    if (BF16OUT) {
      ushort4 u;
      u.x = f2bf(o[0]); u.y = f2bf(o[1]); u.z = f2bf(o[2]); u.w = f2bf(o[3]);
      *(ushort4*)((unsigned short*)Cv + co) = u;
    } else {
      *(float4*)((float*)Cv + co) = make_float4(o[0], o[1], o[2], o[3]);
    }
  }
}

// ---------- per-node gather ----------
__global__ __launch_bounds__(256)
void k_gather(const float* __restrict__ HW, const float* __restrict__ dis,
              const int* __restrict__ rp, const int* __restrict__ ssrc,
              const float* __restrict__ bias, float* __restrict__ Hout, int E) {
  int gw = (blockIdx.x * 256 + threadIdx.x) >> 6;   // one wave per node
  int lane = threadIdx.x & 63;
  if (gw >= NN) return;
  int c = lane * 2;
  float ax = 0.f, ay = 0.f;
#pragma unroll
  for (int r = 0; r < 3; r++) {
    const float* HWr = HW + (long long)r * NN * HF;
    const float* disr = dis + r * NN;
    float di = disr[gw];
    float2 self = *(const float2*)(HWr + (long long)gw * HF + c);
    float2 bb = *(const float2*)(bias + r * HF + c);
    float d2 = di * di;
    ax += bb.x + self.x * d2;
    ay += bb.y + self.y * d2;
    int e = rp[r * (NN + 1) + gw];
    int end = rp[r * (NN + 1) + gw + 1];
    const int* sp = ssrc + (long long)r * E;
    for (; e + 4 <= end; e += 4) {
      int s0 = sp[e], s1 = sp[e + 1], s2 = sp[e + 2], s3 = sp[e + 3];
      float c0 = disr[s0] * di, c1 = disr[s1] * di, c2 = disr[s2] * di, c3 = disr[s3] * di;
      float2 v0 = *(const float2*)(HWr + (long long)s0 * HF + c);
      float2 v1 = *(const float2*)(HWr + (long long)s1 * HF + c);
      float2 v2 = *(const float2*)(HWr + (long long)s2 * HF + c);
      float2 v3 = *(const float2*)(HWr + (long long)s3 * HF + c);
      ax += v0.x * c0 + v1.x * c1 + v2.x * c2 + v3.x * c3;
      ay += v0.y * c0 + v1.y * c1 + v2.y * c2 + v3.y * c3;
    }
    for (; e < end; e++) {
      int s = sp[e];
      float cc = disr[s] * di;
      float2 v = *(const float2*)(HWr + (long long)s * HF + c);
      ax += v.x * cc; ay += v.y * cc;
    }
  }
  float2 o; o.x = fmaxf(ax, 0.f); o.y = fmaxf(ay, 0.f);
  *(float2*)(Hout + (long long)gw * HF + c) = o;
}

extern "C" void kernel_launch(void* const* d_in, const int* in_sizes, int n_in,
                              void* d_out, int out_size, void* d_ws, size_t ws_size,
                              hipStream_t stream) {
  const void* x  = d_in[0];
  const void* ei = d_in[1];
  const void* ew = d_in[2];
  const void* eb = d_in[3];
  const void* w0 = d_in[4];
  const void* b0 = d_in[5];
  const void* w1 = d_in[6];
  const void* b1 = d_in[7];
  const void* lw = d_in[8];
  const void* lb = d_in[9];
  const int E = in_sizes[1] / 6;   // 800000
  const int E3 = 3 * E;

  char* w = (char*)d_ws;
  auto alloc = [&](size_t bytes) -> char* {
    char* p = w; w += (bytes + 255) & ~(size_t)255; return p;
  };
  float* H      = (float*)alloc((size_t)NN * HF * 4);
  float* HW     = (float*)alloc((size_t)3 * NN * HF * 4);
  float* Wf     = (float*)alloc((size_t)N_WF * 4);
  int*   deg    = (int*)alloc((size_t)3 * NN * 4);
  float* dis    = (float*)alloc((size_t)3 * NN * 4);
  int*   rp     = (int*)alloc((size_t)3 * (NN + 1) * 4);
  int*   cursor = (int*)alloc((size_t)3 * NN * 4);
  int*   tiles  = (int*)alloc((size_t)2 * 3 * NT_TILES * 4);
  int*   ssrc   = (int*)alloc((size_t)E3 * 4);
  int*   modes  = (int*)alloc(256);
  int* tilesum = tiles;
  int* tileoff = tiles + 3 * NT_TILES;

  k_detect<<<1, 256, 0, stream>>>(x, ei, modes);
  hipMemsetAsync(deg, 0, (size_t)3 * NN * 4, stream);
  k_convert<<<(N_WF + 255) / 256, 256, 0, stream>>>(ew, eb, w0, b0, w1, b1, lw, lb, modes, Wf);
  k_hist<<<(E3 + 255) / 256, 256, 0, stream>>>(ei, modes, deg, E3, E);
  k_dis<<<(3 * NN + 255) / 256, 256, 0, stream>>>(deg, dis);
  k_tilesum<<<3 * NT_TILES, 256, 0, stream>>>(deg, tilesum);
  k_scantiles<<<1, 256, 0, stream>>>(tilesum, tileoff, rp);
  k_rowptr<<<3 * NT_TILES, 256, 0, stream>>>(deg, tileoff, rp, cursor);
  k_scatter<<<(E3 + 255) / 256, 256, 0, stream>>>(ei, modes, cursor, ssrc, E3, E);

  const int gm = (NN + 63) / 64;
  // embed: H = relu(x @ embW + embB)   [50000,300]x[300,128]
  k_gemm<64, 128, 32, 8, 4, 256, true, true, true, false>
      <<<dim3(gm, 1, 1), 256, 0, stream>>>(x, Wf + OFF_EMBW, Wf + OFF_EMBB, H,
                                           NN, 128, KIN, 0, 0, modes);
  // two GCN layers
  for (int layer = 0; layer < 2; layer++) {
    const float* wB = Wf + (layer == 0 ? OFF_W0 : OFF_W1);
    const float* bB = Wf + (layer == 0 ? OFF_B0 : OFF_B1);
    k_gemm<64, 128, 32, 8, 4, 256, false, false, false, false>
        <<<dim3(gm, 1, 3), 256, 0, stream>>>(H, wB, nullptr, HW,
                                             NN, 128, 128, (long long)128 * 128,
                                             (long long)NN * 128, modes);
    k_gather<<<(NN + 3) / 4, 256, 0, stream>>>(HW, dis, rp, ssrc, bB, H, E);
  }
  // final: out = H @ lin + linB  -> fp32 (reference output dtype is float32)
  k_gemm<64, 64, 32, 4, 4, 256, false, false, true, false>
      <<<dim3(gm, 1, 1), 256, 0, stream>>>(H, Wf + OFF_LIN, Wf + OFF_LINB, d_out,
                                           NN, 64, 128, 0, 0, modes);
}

// Round 3
// 886.027 us; speedup vs baseline: 1.1166x; 1.1166x over previous
//
#include <hip/hip_runtime.h>
#include <hip/hip_bf16.h>
#include <stdint.h>

#define NN 50000
#define HF 128
#define KIN 300
#define TILE1K 1024
#define NT_TILES 49   // ceil(50000/1024)

typedef __attribute__((ext_vector_type(8))) short short8v;
typedef __attribute__((ext_vector_type(4))) float f32x4;

// ---------- bf16 helpers ----------
__device__ __forceinline__ float bf2f(unsigned short u) {
  union { unsigned int i; float f; } c; c.i = ((unsigned int)u) << 16; return c.f;
}
__device__ __forceinline__ unsigned short f2bf(float f) {
  union { float f; unsigned int i; } c; c.f = f;
  unsigned int x = c.i;
  unsigned int lsb = (x >> 16) & 1u;
  x += 0x7fffu + lsb;
  return (unsigned short)(x >> 16);
}

// ---------- runtime dtype detection ----------
__global__ void k_detect(const void* x, const void* ei, int* modes) {
  __shared__ int cnt[2];
  int t = threadIdx.x;
  if (t < 2) cnt[t] = 0;
  __syncthreads();
  if (t < 64) {
    unsigned short u = ((const unsigned short*)x)[2 * t];
    unsigned e = (u >> 7) & 0xFFu;
    bool sane = (u == 0) || (e >= 96u && e <= 136u);
    if (!sane) atomicAdd(&cnt[0], 1);
  } else if (t < 192) {
    int i = t - 64;
    int v = ((const int*)ei)[2 * i + 1];
    if (v != 0) atomicAdd(&cnt[1], 1);
  }
  __syncthreads();
  if (t == 0) { modes[0] = (cnt[0] == 0) ? 1 : 0; modes[1] = (cnt[1] == 0) ? 1 : 0; }
}

// ---------- weight prep: permute to MFMA-B fragment layout (bf16) + fp32 biases ----
// BpE:  [ks10][t8][lane64][i8]   from emb_w [300][128] (K zero-padded to 320)
// BpW0: [r3][ks4][t8][lane64][i8] from w0 [3][128][128]
// BpW1: same from w1
// BpL:  [ks4][t4][lane64][i8]     from lin [128][64]
// biasF: embB[0..128) b0[128..512) b1[512..896) linB[896..960)
__global__ void k_prep(const void* ew, const void* eb, const void* w0, const void* b0,
                       const void* w1, const void* b1, const void* lw, const void* lb,
                       const int* __restrict__ modes,
                       unsigned short* __restrict__ BpE, unsigned short* __restrict__ BpW0,
                       unsigned short* __restrict__ BpW1, unsigned short* __restrict__ BpL,
                       float* __restrict__ biasF) {
  int tid = blockIdx.x * blockDim.x + threadIdx.x;
  const int m = modes[0];
  auto ldb = [&](const void* p, int idx) -> unsigned short {
    return m ? ((const unsigned short*)p)[idx] : f2bf(((const float*)p)[idx]);
  };
  auto ldf = [&](const void* p, int idx) -> float {
    return m ? bf2f(((const unsigned short*)p)[idx]) : ((const float*)p)[idx];
  };
  int e = tid;
  if (e < 40960) {
    int i = e & 7, l = (e >> 3) & 63, t = (e >> 9) & 7, ks = e >> 12;
    int k = ks * 32 + (l >> 4) * 8 + i, n = t * 16 + (l & 15);
    BpE[e] = (k < KIN) ? ldb(ew, k * 128 + n) : (unsigned short)0;
    return;
  }
  e -= 40960;
  if (e < 49152) {
    int i = e & 7, l = (e >> 3) & 63, t = (e >> 9) & 7, ks = (e >> 12) & 3, r = e >> 14;
    int k = ks * 32 + (l >> 4) * 8 + i, n = t * 16 + (l & 15);
    BpW0[e] = ldb(w0, r * 16384 + k * 128 + n);
    return;
  }
  e -= 49152;
  if (e < 49152) {
    int i = e & 7, l = (e >> 3) & 63, t = (e >> 9) & 7, ks = (e >> 12) & 3, r = e >> 14;
    int k = ks * 32 + (l >> 4) * 8 + i, n = t * 16 + (l & 15);
    BpW1[e] = ldb(w1, r * 16384 + k * 128 + n);
    return;
  }
  e -= 49152;
  if (e < 8192) {
    int i = e & 7, l = (e >> 3) & 63, t = (e >> 9) & 3, ks = e >> 11;
    int k = ks * 32 + (l >> 4) * 8 + i, n = t * 16 + (l & 15);
    BpL[e] = ldb(lw, k * 64 + n);
    return;
  }
  e -= 8192;
  if (e < 960) {
    float v;
    if (e < 128) v = ldf(eb, e);
    else if (e < 512) v = ldf(b0, e - 128);
    else if (e < 896) v = ldf(b1, e - 512);
    else v = ldf(lb, e - 896);
    biasF[e] = v;
  }
}

// ---------- pad/copy x -> Xp [NN][320] bf16 ----------
__global__ void k_xp(const void* x, const int* __restrict__ modes, unsigned short* __restrict__ Xp) {
  int tid = blockIdx.x * blockDim.x + threadIdx.x;
  if (tid >= NN * 320) return;
  int row = tid / 320, c = tid - row * 320;
  unsigned short v = 0;
  if (c < KIN)
    v = modes[0] ? ((const unsigned short*)x)[row * KIN + c]
                 : f2bf(((const float*)x)[row * KIN + c]);
  Xp[tid] = v;
}

// ---------- degree histogram ----------
__global__ void k_hist(const void* ei, const int* __restrict__ modes,
                       int* __restrict__ deg, int E3, int E) {
  int t = blockIdx.x * blockDim.x + threadIdx.x;
  if (t >= E3) return;
  int r = t / E, i = t - r * E;
  long long j = (long long)r * 2 * E + E + i;  // dst
  int d = modes[1] ? (int)((const long long*)ei)[j] : ((const int*)ei)[j];
  atomicAdd(&deg[r * NN + d], 1);
}

__global__ void k_dis(const int* __restrict__ deg, float* __restrict__ dis) {
  int t = blockIdx.x * blockDim.x + threadIdx.x;
  if (t < 3 * NN) dis[t] = rsqrtf((float)deg[t] + 1.0f);
}

// ---------- CSR build ----------
__global__ __launch_bounds__(256) void k_tilesum(const int* __restrict__ deg, int* __restrict__ tilesum) {
  int b = blockIdx.x;
  int r = b / NT_TILES, tt = b - r * NT_TILES;
  int base = tt * TILE1K + threadIdx.x * 4;
  int s = 0;
#pragma unroll
  for (int j = 0; j < 4; j++) { int i = base + j; if (i < NN) s += deg[r * NN + i]; }
  __shared__ int red[256];
  red[threadIdx.x] = s; __syncthreads();
  for (int st = 128; st > 0; st >>= 1) {
    if (threadIdx.x < st) red[threadIdx.x] += red[threadIdx.x + st];
    __syncthreads();
  }
  if (threadIdx.x == 0) tilesum[b] = red[0];
}

__global__ void k_scantiles(const int* __restrict__ tilesum, int* __restrict__ tileoff,
                            int* __restrict__ rp) {
  __shared__ int s[3 * NT_TILES];
  int t = threadIdx.x;
  if (t < 3 * NT_TILES) s[t] = tilesum[t];
  __syncthreads();
  if (t == 0) {
    for (int r = 0; r < 3; r++) {
      int run = 0;
      for (int i = 0; i < NT_TILES; i++) { int v = s[r * NT_TILES + i]; s[r * NT_TILES + i] = run; run += v; }
      rp[r * (NN + 1) + NN] = run;
    }
  }
  __syncthreads();
  if (t < 3 * NT_TILES) tileoff[t] = s[t];
}

__global__ __launch_bounds__(256) void k_rowptr(const int* __restrict__ deg, const int* __restrict__ tileoff,
                                                int* __restrict__ rp, int* __restrict__ cursor) {
  int b = blockIdx.x;
  int r = b / NT_TILES, tt = b - r * NT_TILES;
  int tid = threadIdx.x;
  int base = tt * TILE1K + tid * 4;
  int v[4]; int tsum = 0;
#pragma unroll
  for (int j = 0; j < 4; j++) { int i = base + j; v[j] = (i < NN) ? deg[r * NN + i] : 0; tsum += v[j]; }
  int lane = tid & 63;
  int x = tsum;
  for (int off = 1; off < 64; off <<= 1) {
    int y = __shfl_up(x, off);
    if (lane >= off) x += y;
  }
  __shared__ int wsum[4];
  int wv = tid >> 6;
  if (lane == 63) wsum[wv] = x;
  __syncthreads();
  int run = tileoff[b] + (x - tsum);
  for (int k2 = 0; k2 < wv; k2++) run += wsum[k2];
#pragma unroll
  for (int j = 0; j < 4; j++) {
    int i = base + j;
    if (i < NN) { rp[r * (NN + 1) + i] = run; cursor[r * NN + i] = run; }
    run += v[j];
  }
}

__global__ void k_scatter(const void* ei, const int* __restrict__ modes,
                          int* __restrict__ cursor, int* __restrict__ ssrc, int E3, int E) {
  int t = blockIdx.x * blockDim.x + threadIdx.x;
  if (t >= E3) return;
  int r = t / E, i = t - r * E;
  long long jb = (long long)r * 2 * E;
  int s, d;
  if (modes[1]) { const long long* p = (const long long*)ei; s = (int)p[jb + i]; d = (int)p[jb + E + i]; }
  else          { const int* p = (const int*)ei;             s = p[jb + i];      d = p[jb + E + i]; }
  int pos = atomicAdd(&cursor[r * NN + d], 1);
  ssrc[(long long)r * E + pos] = s;
}

// ---------- MFMA GEMM: C[M,N] = A[M,K] @ B[K,N] (+bias)(relu), A bf16 (or hi/lo split) ----
// Block = 256 threads = 4 waves; each wave does 16 rows x N cols.
// A-frag: row = lane&15, k = 8*(lane>>4)+i.  B pre-permuted lane-contiguous.
// C/D: col = lane&15, row = (lane>>4)*4+reg  [m89-verified].
template<int KSTEPS, int NTILES, int ASTR, bool SPLIT, bool RELU, bool BIAS, bool SPLITOUT>
__global__ __launch_bounds__(256)
void k_mgemm(const unsigned short* __restrict__ Ahi, const unsigned short* __restrict__ Alo,
             const unsigned short* __restrict__ Bp, const float* __restrict__ bias,
             float* __restrict__ Cf, unsigned short* __restrict__ Chi,
             unsigned short* __restrict__ Clo, int N, long long sBz, long long sCz) {
  int wave = threadIdx.x >> 6, lane = threadIdx.x & 63;
  int rowbase = blockIdx.x * 64 + wave * 16;
  if (rowbase >= NN) return;
  int z = blockIdx.z;
  int lr = lane & 15, lg = lane >> 4;
  const unsigned short* Bz = Bp + (long long)z * sBz;
  f32x4 acc[NTILES];
#pragma unroll
  for (int t = 0; t < NTILES; t++) acc[t] = (f32x4){0.f, 0.f, 0.f, 0.f};
  const unsigned short* ah = Ahi + (long long)(rowbase + lr) * ASTR + lg * 8;
  const unsigned short* al = Alo + (long long)(rowbase + lr) * ASTR + lg * 8;
#pragma unroll
  for (int ks = 0; ks < KSTEPS; ks++) {
    short8v a0 = *(const short8v*)(ah + ks * 32);
    short8v a1;
    if (SPLIT) a1 = *(const short8v*)(al + ks * 32);
#pragma unroll
    for (int t = 0; t < NTILES; t++) {
      short8v b = *(const short8v*)(Bz + (((long long)ks * NTILES + t) * 64 + lane) * 8);
      acc[t] = __builtin_amdgcn_mfma_f32_16x16x32_bf16(a0, b, acc[t], 0, 0, 0);
      if (SPLIT) acc[t] = __builtin_amdgcn_mfma_f32_16x16x32_bf16(a1, b, acc[t], 0, 0, 0);
    }
  }
#pragma unroll
  for (int t = 0; t < NTILES; t++) {
    int col = t * 16 + lr;
    float bv = BIAS ? bias[col] : 0.f;
#pragma unroll
    for (int reg = 0; reg < 4; reg++) {
      int row = rowbase + lg * 4 + reg;
      float v = acc[t][reg] + bv;
      if (RELU) v = fmaxf(v, 0.f);
      if (SPLITOUT) {
        unsigned short h = f2bf(v);
        float resid = v - bf2f(h);
        Chi[(long long)row * N + col] = h;
        Clo[(long long)row * N + col] = f2bf(resid);
      } else {
        Cf[(long long)z * sCz + (long long)row * N + col] = v;
      }
    }
  }
}

// ---------- per-node gather: Hout = relu(sum_r [b_r + HW_r[i]*d2 + sum_e coef*HW_r[src]]), split-write
__global__ __launch_bounds__(256)
void k_gather(const float* __restrict__ HW, const float* __restrict__ dis,
              const int* __restrict__ rp, const int* __restrict__ ssrc,
              const float* __restrict__ bias, unsigned short* __restrict__ Hhi,
              unsigned short* __restrict__ Hlo, int E) {
  int gw = (blockIdx.x * 256 + threadIdx.x) >> 6;   // one wave per node
  int lane = threadIdx.x & 63;
  if (gw >= NN) return;
  int c = lane * 2;
  float ax = 0.f, ay = 0.f;
#pragma unroll
  for (int r = 0; r < 3; r++) {
    const float* HWr = HW + (long long)r * NN * HF;
    const float* disr = dis + r * NN;
    float di = disr[gw];
    float2 self = *(const float2*)(HWr + (long long)gw * HF + c);
    float2 bb = *(const float2*)(bias + r * HF + c);
    float d2 = di * di;
    ax += bb.x + self.x * d2;
    ay += bb.y + self.y * d2;
    int e = rp[r * (NN + 1) + gw];
    int end = rp[r * (NN + 1) + gw + 1];
    const int* sp = ssrc + (long long)r * E;
    for (; e + 4 <= end; e += 4) {
      int s0 = sp[e], s1 = sp[e + 1], s2 = sp[e + 2], s3 = sp[e + 3];
      float c0 = disr[s0] * di, c1 = disr[s1] * di, c2 = disr[s2] * di, c3 = disr[s3] * di;
      float2 v0 = *(const float2*)(HWr + (long long)s0 * HF + c);
      float2 v1 = *(const float2*)(HWr + (long long)s1 * HF + c);
      float2 v2 = *(const float2*)(HWr + (long long)s2 * HF + c);
      float2 v3 = *(const float2*)(HWr + (long long)s3 * HF + c);
      ax += v0.x * c0 + v1.x * c1 + v2.x * c2 + v3.x * c3;
      ay += v0.y * c0 + v1.y * c1 + v2.y * c2 + v3.y * c3;
    }
    for (; e < end; e++) {
      int s = sp[e];
      float cc = disr[s] * di;
      float2 v = *(const float2*)(HWr + (long long)s * HF + c);
      ax += v.x * cc; ay += v.y * cc;
    }
  }
  float vx = fmaxf(ax, 0.f), vy = fmaxf(ay, 0.f);
  ushort2 hi2, lo2;
  hi2.x = f2bf(vx); lo2.x = f2bf(vx - bf2f(hi2.x));
  hi2.y = f2bf(vy); lo2.y = f2bf(vy - bf2f(hi2.y));
  long long o = (long long)gw * HF + c;
  *(ushort2*)(Hhi + o) = hi2;
  *(ushort2*)(Hlo + o) = lo2;
}

extern "C" void kernel_launch(void* const* d_in, const int* in_sizes, int n_in,
                              void* d_out, int out_size, void* d_ws, size_t ws_size,
                              hipStream_t stream) {
  const void* x  = d_in[0];
  const void* ei = d_in[1];
  const void* ew = d_in[2];
  const void* eb = d_in[3];
  const void* w0 = d_in[4];
  const void* b0 = d_in[5];
  const void* w1 = d_in[6];
  const void* b1 = d_in[7];
  const void* lw = d_in[8];
  const void* lb = d_in[9];
  const int E = in_sizes[1] / 6;   // 800000
  const int E3 = 3 * E;

  char* w = (char*)d_ws;
  auto alloc = [&](size_t bytes) -> char* {
    char* p = w; w += (bytes + 255) & ~(size_t)255; return p;
  };
  unsigned short* Hhi = (unsigned short*)alloc((size_t)NN * HF * 2);
  unsigned short* Hlo = (unsigned short*)alloc((size_t)NN * HF * 2);
  float* HW           = (float*)alloc((size_t)3 * NN * HF * 4);
  unsigned short* Xp  = (unsigned short*)HW;   // alias: Xp consumed before HW written
  unsigned short* BpE = (unsigned short*)alloc(40960 * 2);
  unsigned short* BpW0= (unsigned short*)alloc(49152 * 2);
  unsigned short* BpW1= (unsigned short*)alloc(49152 * 2);
  unsigned short* BpL = (unsigned short*)alloc(8192 * 2);
  float* biasF        = (float*)alloc(960 * 4);
  int*   deg    = (int*)alloc((size_t)3 * NN * 4);
  float* dis    = (float*)alloc((size_t)3 * NN * 4);
  int*   rp     = (int*)alloc((size_t)3 * (NN + 1) * 4);
  int*   cursor = (int*)alloc((size_t)3 * NN * 4);
  int*   tiles  = (int*)alloc((size_t)2 * 3 * NT_TILES * 4);
  int*   ssrc   = (int*)alloc((size_t)E3 * 4);
  int*   modes  = (int*)alloc(256);
  int* tilesum = tiles;
  int* tileoff = tiles + 3 * NT_TILES;

  k_detect<<<1, 256, 0, stream>>>(x, ei, modes);
  hipMemsetAsync(deg, 0, (size_t)3 * NN * 4, stream);
  k_prep<<<(148416 + 255) / 256, 256, 0, stream>>>(ew, eb, w0, b0, w1, b1, lw, lb,
                                                   modes, BpE, BpW0, BpW1, BpL, biasF);
  k_xp<<<(NN * 320 + 255) / 256, 256, 0, stream>>>(x, modes, Xp);
  k_hist<<<(E3 + 255) / 256, 256, 0, stream>>>(ei, modes, deg, E3, E);
  k_dis<<<(3 * NN + 255) / 256, 256, 0, stream>>>(deg, dis);
  k_tilesum<<<3 * NT_TILES, 256, 0, stream>>>(deg, tilesum);
  k_scantiles<<<1, 256, 0, stream>>>(tilesum, tileoff, rp);
  k_rowptr<<<3 * NT_TILES, 256, 0, stream>>>(deg, tileoff, rp, cursor);
  k_scatter<<<(E3 + 255) / 256, 256, 0, stream>>>(ei, modes, cursor, ssrc, E3, E);

  const int gm = (NN + 63) / 64;  // 782
  // embed: Hhi/Hlo = split(relu(x @ embW + embB)); A = x exact bf16 (K padded to 320)
  k_mgemm<10, 8, 320, false, true, true, true>
      <<<dim3(gm, 1, 1), 256, 0, stream>>>(Xp, Xp, BpE, biasF, nullptr, Hhi, Hlo, 128, 0, 0);
  // two GCN layers
  for (int layer = 0; layer < 2; layer++) {
    const unsigned short* Bp = layer == 0 ? BpW0 : BpW1;
    const float* bB = biasF + (layer == 0 ? 128 : 512);
    k_mgemm<4, 8, 128, true, false, false, false>
        <<<dim3(gm, 1, 3), 256, 0, stream>>>(Hhi, Hlo, Bp, nullptr, HW, nullptr, nullptr,
                                             128, 16384, (long long)NN * 128);
    k_gather<<<(NN + 3) / 4, 256, 0, stream>>>(HW, dis, rp, ssrc, bB, Hhi, Hlo, E);
  }
  // final: out = H @ lin + linB -> fp32
  k_mgemm<4, 4, 128, true, false, true, false>
      <<<dim3(gm, 1, 1), 256, 0, stream>>>(Hhi, Hlo, BpL, biasF + 896, (float*)d_out,
                                           nullptr, nullptr, 64, 0, 0);
}

// Round 4
// 648.554 us; speedup vs baseline: 1.5254x; 1.3662x over previous
//
#include <hip/hip_runtime.h>
#include <hip/hip_bf16.h>
#include <stdint.h>

#define NN 50000
#define HF 128
#define KIN 300
#define TILE1K 1024
#define NT_TILES 49   // ceil(50000/1024)

typedef __attribute__((ext_vector_type(8))) short short8v;
typedef __attribute__((ext_vector_type(4))) float f32x4;
typedef _Float16 f16x2 __attribute__((ext_vector_type(2)));

// ---------- bf16 helpers ----------
__device__ __forceinline__ float bf2f(unsigned short u) {
  union { unsigned int i; float f; } c; c.i = ((unsigned int)u) << 16; return c.f;
}
__device__ __forceinline__ unsigned short f2bf(float f) {
  union { float f; unsigned int i; } c; c.f = f;
  unsigned int x = c.i;
  unsigned int lsb = (x >> 16) & 1u;
  x += 0x7fffu + lsb;
  return (unsigned short)(x >> 16);
}

// ---------- runtime dtype detection ----------
__global__ void k_detect(const void* x, const void* ei, int* modes) {
  __shared__ int cnt[2];
  int t = threadIdx.x;
  if (t < 2) cnt[t] = 0;
  __syncthreads();
  if (t < 64) {
    unsigned short u = ((const unsigned short*)x)[2 * t];
    unsigned e = (u >> 7) & 0xFFu;
    bool sane = (u == 0) || (e >= 96u && e <= 136u);
    if (!sane) atomicAdd(&cnt[0], 1);
  } else if (t < 192) {
    int i = t - 64;
    int v = ((const int*)ei)[2 * i + 1];
    if (v != 0) atomicAdd(&cnt[1], 1);
  }
  __syncthreads();
  if (t == 0) { modes[0] = (cnt[0] == 0) ? 1 : 0; modes[1] = (cnt[1] == 0) ? 1 : 0; }
}

// ---------- weight prep: permute to MFMA-B fragment layout (bf16) + fp32 biases ----
__global__ void k_prep(const void* ew, const void* eb, const void* w0, const void* b0,
                       const void* w1, const void* b1, const void* lw, const void* lb,
                       const int* __restrict__ modes,
                       unsigned short* __restrict__ BpE, unsigned short* __restrict__ BpW0,
                       unsigned short* __restrict__ BpW1, unsigned short* __restrict__ BpL,
                       float* __restrict__ biasF) {
  int tid = blockIdx.x * blockDim.x + threadIdx.x;
  const int m = modes[0];
  auto ldb = [&](const void* p, int idx) -> unsigned short {
    return m ? ((const unsigned short*)p)[idx] : f2bf(((const float*)p)[idx]);
  };
  auto ldf = [&](const void* p, int idx) -> float {
    return m ? bf2f(((const unsigned short*)p)[idx]) : ((const float*)p)[idx];
  };
  int e = tid;
  if (e < 40960) {
    int i = e & 7, l = (e >> 3) & 63, t = (e >> 9) & 7, ks = e >> 12;
    int k = ks * 32 + (l >> 4) * 8 + i, n = t * 16 + (l & 15);
    BpE[e] = (k < KIN) ? ldb(ew, k * 128 + n) : (unsigned short)0;
    return;
  }
  e -= 40960;
  if (e < 49152) {
    int i = e & 7, l = (e >> 3) & 63, t = (e >> 9) & 7, ks = (e >> 12) & 3, r = e >> 14;
    int k = ks * 32 + (l >> 4) * 8 + i, n = t * 16 + (l & 15);
    BpW0[e] = ldb(w0, r * 16384 + k * 128 + n);
    return;
  }
  e -= 49152;
  if (e < 49152) {
    int i = e & 7, l = (e >> 3) & 63, t = (e >> 9) & 7, ks = (e >> 12) & 3, r = e >> 14;
    int k = ks * 32 + (l >> 4) * 8 + i, n = t * 16 + (l & 15);
    BpW1[e] = ldb(w1, r * 16384 + k * 128 + n);
    return;
  }
  e -= 49152;
  if (e < 8192) {
    int i = e & 7, l = (e >> 3) & 63, t = (e >> 9) & 3, ks = e >> 11;
    int k = ks * 32 + (l >> 4) * 8 + i, n = t * 16 + (l & 15);
    BpL[e] = ldb(lw, k * 64 + n);
    return;
  }
  e -= 8192;
  if (e < 960) {
    float v;
    if (e < 128) v = ldf(eb, e);
    else if (e < 512) v = ldf(b0, e - 128);
    else if (e < 896) v = ldf(b1, e - 512);
    else v = ldf(lb, e - 896);
    biasF[e] = v;
  }
}

// ---------- degree histogram: 8 shadow copies (XCD-local atomics) ----------
__global__ void k_hist(const void* ei, const int* __restrict__ modes,
                       int* __restrict__ deg8, int E3, int E) {
  int t = blockIdx.x * blockDim.x + threadIdx.x;
  if (t >= E3) return;
  int r = t / E, i = t - r * E;
  long long j = (long long)r * 2 * E + E + i;  // dst
  int d = modes[1] ? (int)((const long long*)ei)[j] : ((const int*)ei)[j];
  atomicAdd(&deg8[(blockIdx.x & 7) * 3 * NN + r * NN + d], 1);
}

// deg[t] = sum of 8 copies; dis[t] = rsqrt(deg+1)
__global__ void k_degsum(const int* __restrict__ deg8, int* __restrict__ deg,
                         float* __restrict__ dis) {
  int t = blockIdx.x * blockDim.x + threadIdx.x;
  if (t >= 3 * NN) return;
  int s = 0;
#pragma unroll
  for (int c = 0; c < 8; c++) s += deg8[c * 3 * NN + t];
  deg[t] = s;
  dis[t] = rsqrtf((float)s + 1.0f);
}

// ---------- CSR build ----------
__global__ __launch_bounds__(256) void k_tilesum(const int* __restrict__ deg, int* __restrict__ tilesum) {
  int b = blockIdx.x;
  int r = b / NT_TILES, tt = b - r * NT_TILES;
  int base = tt * TILE1K + threadIdx.x * 4;
  int s = 0;
#pragma unroll
  for (int j = 0; j < 4; j++) { int i = base + j; if (i < NN) s += deg[r * NN + i]; }
  __shared__ int red[256];
  red[threadIdx.x] = s; __syncthreads();
  for (int st = 128; st > 0; st >>= 1) {
    if (threadIdx.x < st) red[threadIdx.x] += red[threadIdx.x + st];
    __syncthreads();
  }
  if (threadIdx.x == 0) tilesum[b] = red[0];
}

__global__ void k_scantiles(const int* __restrict__ tilesum, int* __restrict__ tileoff,
                            int* __restrict__ rp) {
  __shared__ int s[3 * NT_TILES];
  int t = threadIdx.x;
  if (t < 3 * NT_TILES) s[t] = tilesum[t];
  __syncthreads();
  if (t == 0) {
    for (int r = 0; r < 3; r++) {
      int run = 0;
      for (int i = 0; i < NT_TILES; i++) { int v = s[r * NT_TILES + i]; s[r * NT_TILES + i] = run; run += v; }
      rp[r * (NN + 1) + NN] = run;
    }
  }
  __syncthreads();
  if (t < 3 * NT_TILES) tileoff[t] = s[t];
}

__global__ __launch_bounds__(256) void k_rowptr(const int* __restrict__ deg, const int* __restrict__ tileoff,
                                                int* __restrict__ rp, int* __restrict__ cursor) {
  int b = blockIdx.x;
  int r = b / NT_TILES, tt = b - r * NT_TILES;
  int tid = threadIdx.x;
  int base = tt * TILE1K + tid * 4;
  int v[4]; int tsum = 0;
#pragma unroll
  for (int j = 0; j < 4; j++) { int i = base + j; v[j] = (i < NN) ? deg[r * NN + i] : 0; tsum += v[j]; }
  int lane = tid & 63;
  int x = tsum;
  for (int off = 1; off < 64; off <<= 1) {
    int y = __shfl_up(x, off);
    if (lane >= off) x += y;
  }
  __shared__ int wsum[4];
  int wv = tid >> 6;
  if (lane == 63) wsum[wv] = x;
  __syncthreads();
  int run = tileoff[b] + (x - tsum);
  for (int k2 = 0; k2 < wv; k2++) run += wsum[k2];
#pragma unroll
  for (int j = 0; j < 4; j++) {
    int i = base + j;
    if (i < NN) { rp[r * (NN + 1) + i] = run; cursor[r * NN + i] = run; }
    run += v[j];
  }
}

__global__ void k_scatter(const void* ei, const int* __restrict__ modes,
                          int* __restrict__ cursor, unsigned short* __restrict__ ssrc,
                          int E3, int E) {
  int t = blockIdx.x * blockDim.x + threadIdx.x;
  if (t >= E3) return;
  int r = t / E, i = t - r * E;
  long long jb = (long long)r * 2 * E;
  int s, d;
  if (modes[1]) { const long long* p = (const long long*)ei; s = (int)p[jb + i]; d = (int)p[jb + E + i]; }
  else          { const int* p = (const int*)ei;             s = p[jb + i];      d = p[jb + E + i]; }
  int pos = atomicAdd(&cursor[r * NN + d], 1);
  ssrc[(long long)r * E + pos] = (unsigned short)s;
}

// ---------- MFMA GEMM ----------
// OUTMODE: 0 = fp32 to Cout, 1 = fp16 to Cout, 2 = bf16 hi/lo split to Chi/Clo
// AX: A is raw x [NN][KIN] (bf16 or fp32 per modes[0]), K zero-padded to KSTEPS*32
template<int KSTEPS, int NTILES, int ASTR, bool AX, bool SPLIT, bool RELU, bool BIAS, int OUTMODE>
__global__ __launch_bounds__(256)
void k_mgemm(const void* __restrict__ Ahi_, const unsigned short* __restrict__ Alo,
             const unsigned short* __restrict__ Bp, const float* __restrict__ bias,
             void* __restrict__ Cout, unsigned short* __restrict__ Chi,
             unsigned short* __restrict__ Clo, int N, long long sBz, long long sCz,
             const int* __restrict__ modes) {
  int wave = threadIdx.x >> 6, lane = threadIdx.x & 63;
  int rowbase = blockIdx.x * 64 + wave * 16;
  if (rowbase >= NN) return;
  int z = blockIdx.z;
  int lr = lane & 15, lg = lane >> 4;
  const unsigned short* Bz = Bp + (long long)z * sBz;
  f32x4 acc[NTILES];
#pragma unroll
  for (int t = 0; t < NTILES; t++) acc[t] = (f32x4){0.f, 0.f, 0.f, 0.f};
  const unsigned short* ah = nullptr; const unsigned short* al = nullptr;
  int fmode = 1;
  if (!AX) {
    ah = (const unsigned short*)Ahi_ + (long long)(rowbase + lr) * ASTR + lg * 8;
    al = Alo + (long long)(rowbase + lr) * ASTR + lg * 8;
  } else {
    fmode = modes[0];
  }
#pragma unroll
  for (int ks = 0; ks < KSTEPS; ks++) {
    short8v a0, a1;
    if (AX) {
      union { unsigned int u[4]; short8v v; } tt;
      if (fmode) {
        const unsigned int* xu = (const unsigned int*)Ahi_;
        long long rb = (long long)(rowbase + lr) * (KIN / 2) + ks * 16 + lg * 4;
#pragma unroll
        for (int j = 0; j < 4; j++) {
          int kk = ks * 32 + lg * 8 + 2 * j;
          tt.u[j] = (kk < KIN) ? xu[rb + j] : 0u;
        }
      } else {
        const float* xf = (const float*)Ahi_;
        long long rb = (long long)(rowbase + lr) * KIN;
#pragma unroll
        for (int j = 0; j < 4; j++) {
          int kk = ks * 32 + lg * 8 + 2 * j;
          unsigned short lo_ = (kk < KIN) ? f2bf(xf[rb + kk]) : (unsigned short)0;
          unsigned short hi_ = (kk + 1 < KIN) ? f2bf(xf[rb + kk + 1]) : (unsigned short)0;
          tt.u[j] = (unsigned int)lo_ | ((unsigned int)hi_ << 16);
        }
      }
      a0 = tt.v;
    } else {
      a0 = *(const short8v*)(ah + ks * 32);
      if (SPLIT) a1 = *(const short8v*)(al + ks * 32);
    }
#pragma unroll
    for (int t = 0; t < NTILES; t++) {
      short8v b = *(const short8v*)(Bz + (((long long)ks * NTILES + t) * 64 + lane) * 8);
      acc[t] = __builtin_amdgcn_mfma_f32_16x16x32_bf16(a0, b, acc[t], 0, 0, 0);
      if (SPLIT) acc[t] = __builtin_amdgcn_mfma_f32_16x16x32_bf16(a1, b, acc[t], 0, 0, 0);
    }
  }
#pragma unroll
  for (int t = 0; t < NTILES; t++) {
    int col = t * 16 + lr;
    float bv = BIAS ? bias[col] : 0.f;
#pragma unroll
    for (int reg = 0; reg < 4; reg++) {
      int row = rowbase + lg * 4 + reg;
      float v = acc[t][reg] + bv;
      if (RELU) v = fmaxf(v, 0.f);
      if (OUTMODE == 2) {
        unsigned short h = f2bf(v);
        float resid = v - bf2f(h);
        Chi[(long long)row * N + col] = h;
        Clo[(long long)row * N + col] = f2bf(resid);
      } else if (OUTMODE == 1) {
        ((_Float16*)Cout)[(long long)z * sCz + (long long)row * N + col] = (_Float16)v;
      } else {
        ((float*)Cout)[(long long)z * sCz + (long long)row * N + col] = v;
      }
    }
  }
}

// ---------- per-node gather (fp16 HW, u16 ssrc) ----------
__global__ __launch_bounds__(256)
void k_gather(const _Float16* __restrict__ HW, const float* __restrict__ dis,
              const int* __restrict__ rp, const unsigned short* __restrict__ ssrc,
              const float* __restrict__ bias, unsigned short* __restrict__ Hhi,
              unsigned short* __restrict__ Hlo, int E) {
  int gw = (blockIdx.x * 256 + threadIdx.x) >> 6;   // one wave per node
  int lane = threadIdx.x & 63;
  if (gw >= NN) return;
  int c = lane * 2;
  float ax = 0.f, ay = 0.f;
#pragma unroll
  for (int r = 0; r < 3; r++) {
    const _Float16* HWr = HW + (long long)r * NN * HF;
    const float* disr = dis + r * NN;
    float di = disr[gw];
    f16x2 self = *(const f16x2*)(HWr + (long long)gw * HF + c);
    float2 bb = *(const float2*)(bias + r * HF + c);
    float d2 = di * di;
    ax += bb.x + (float)self.x * d2;
    ay += bb.y + (float)self.y * d2;
    int e = rp[r * (NN + 1) + gw];
    int end = rp[r * (NN + 1) + gw + 1];
    const unsigned short* sp = ssrc + (long long)r * E;
    for (; e + 4 <= end; e += 4) {
      int s0 = sp[e], s1 = sp[e + 1], s2 = sp[e + 2], s3 = sp[e + 3];
      float c0 = disr[s0] * di, c1 = disr[s1] * di, c2 = disr[s2] * di, c3 = disr[s3] * di;
      f16x2 v0 = *(const f16x2*)(HWr + (long long)s0 * HF + c);
      f16x2 v1 = *(const f16x2*)(HWr + (long long)s1 * HF + c);
      f16x2 v2 = *(const f16x2*)(HWr + (long long)s2 * HF + c);
      f16x2 v3 = *(const f16x2*)(HWr + (long long)s3 * HF + c);
      ax += (float)v0.x * c0 + (float)v1.x * c1 + (float)v2.x * c2 + (float)v3.x * c3;
      ay += (float)v0.y * c0 + (float)v1.y * c1 + (float)v2.y * c2 + (float)v3.y * c3;
    }
    for (; e < end; e++) {
      int s = sp[e];
      float cc = disr[s] * di;
      f16x2 v = *(const f16x2*)(HWr + (long long)s * HF + c);
      ax += (float)v.x * cc; ay += (float)v.y * cc;
    }
  }
  float vx = fmaxf(ax, 0.f), vy = fmaxf(ay, 0.f);
  ushort2 hi2, lo2;
  hi2.x = f2bf(vx); lo2.x = f2bf(vx - bf2f(hi2.x));
  hi2.y = f2bf(vy); lo2.y = f2bf(vy - bf2f(hi2.y));
  long long o = (long long)gw * HF + c;
  *(ushort2*)(Hhi + o) = hi2;
  *(ushort2*)(Hlo + o) = lo2;
}

extern "C" void kernel_launch(void* const* d_in, const int* in_sizes, int n_in,
                              void* d_out, int out_size, void* d_ws, size_t ws_size,
                              hipStream_t stream) {
  const void* x  = d_in[0];
  const void* ei = d_in[1];
  const void* ew = d_in[2];
  const void* eb = d_in[3];
  const void* w0 = d_in[4];
  const void* b0 = d_in[5];
  const void* w1 = d_in[6];
  const void* b1 = d_in[7];
  const void* lw = d_in[8];
  const void* lb = d_in[9];
  const int E = in_sizes[1] / 6;   // 800000
  const int E3 = 3 * E;

  char* w = (char*)d_ws;
  auto alloc = [&](size_t bytes) -> char* {
    char* p = w; w += (bytes + 255) & ~(size_t)255; return p;
  };
  unsigned short* Hhi = (unsigned short*)alloc((size_t)NN * HF * 2);
  unsigned short* Hlo = (unsigned short*)alloc((size_t)NN * HF * 2);
  _Float16* HWh       = (_Float16*)alloc((size_t)3 * NN * HF * 2);
  unsigned short* BpE = (unsigned short*)alloc(40960 * 2);
  unsigned short* BpW0= (unsigned short*)alloc(49152 * 2);
  unsigned short* BpW1= (unsigned short*)alloc(49152 * 2);
  unsigned short* BpL = (unsigned short*)alloc(8192 * 2);
  float* biasF        = (float*)alloc(960 * 4);
  int*   deg8   = (int*)alloc((size_t)8 * 3 * NN * 4);
  int*   deg    = (int*)alloc((size_t)3 * NN * 4);
  float* dis    = (float*)alloc((size_t)3 * NN * 4);
  int*   rp     = (int*)alloc((size_t)3 * (NN + 1) * 4);
  int*   cursor = (int*)alloc((size_t)3 * NN * 4);
  int*   tiles  = (int*)alloc((size_t)2 * 3 * NT_TILES * 4);
  unsigned short* ssrc = (unsigned short*)alloc((size_t)E3 * 2);
  int*   modes  = (int*)alloc(256);
  int* tilesum = tiles;
  int* tileoff = tiles + 3 * NT_TILES;

  k_detect<<<1, 256, 0, stream>>>(x, ei, modes);
  hipMemsetAsync(deg8, 0, (size_t)8 * 3 * NN * 4, stream);
  k_prep<<<(148416 + 255) / 256, 256, 0, stream>>>(ew, eb, w0, b0, w1, b1, lw, lb,
                                                   modes, BpE, BpW0, BpW1, BpL, biasF);
  k_hist<<<(E3 + 255) / 256, 256, 0, stream>>>(ei, modes, deg8, E3, E);
  k_degsum<<<(3 * NN + 255) / 256, 256, 0, stream>>>(deg8, deg, dis);
  k_tilesum<<<3 * NT_TILES, 256, 0, stream>>>(deg, tilesum);
  k_scantiles<<<1, 256, 0, stream>>>(tilesum, tileoff, rp);
  k_rowptr<<<3 * NT_TILES, 256, 0, stream>>>(deg, tileoff, rp, cursor);
  k_scatter<<<(E3 + 255) / 256, 256, 0, stream>>>(ei, modes, cursor, ssrc, E3, E);

  const int gm = (NN + 63) / 64;  // 782
  // embed: Hhi/Hlo = split(relu(x @ embW + embB)); A = x read directly (K pad->320)
  k_mgemm<10, 8, 0, true, false, true, true, 2>
      <<<dim3(gm, 1, 1), 256, 0, stream>>>(x, nullptr, BpE, biasF, nullptr, Hhi, Hlo,
                                           128, 0, 0, modes);
  // two GCN layers
  for (int layer = 0; layer < 2; layer++) {
    const unsigned short* Bp = layer == 0 ? BpW0 : BpW1;
    const float* bB = biasF + (layer == 0 ? 128 : 512);
    k_mgemm<4, 8, 128, false, true, false, false, 1>
        <<<dim3(gm, 1, 3), 256, 0, stream>>>(Hhi, Hlo, Bp, nullptr, HWh, nullptr, nullptr,
                                             128, 16384, (long long)NN * 128, modes);
    k_gather<<<(NN + 3) / 4, 256, 0, stream>>>(HWh, dis, rp, ssrc, bB, Hhi, Hlo, E);
  }
  // final: out = H @ lin + linB -> fp32
  k_mgemm<4, 4, 128, false, true, false, true, 0>
      <<<dim3(gm, 1, 1), 256, 0, stream>>>(Hhi, Hlo, BpL, biasF + 896, d_out,
                                           nullptr, nullptr, 64, 0, 0, modes);
}

// Round 5
// 476.143 us; speedup vs baseline: 2.0778x; 1.3621x over previous
//
#include <hip/hip_runtime.h>
#include <hip/hip_bf16.h>
#include <stdint.h>

#define NN 50000
#define HF 128
#define KIN 300
#define TILE1K 1024
#define NBUCK 49            // ceil(50000/1024) buckets per relation
#define NB3 (3 * NBUCK)     // 147
#define BCAP 40960          // bucket capacity (mean ~16330, sigma ~130)
#define PCHUNK 8192         // edges per k_part block

typedef __attribute__((ext_vector_type(8))) short short8v;
typedef __attribute__((ext_vector_type(4))) float f32x4;
typedef _Float16 f16x2 __attribute__((ext_vector_type(2)));

// ---------- bf16 helpers ----------
__device__ __forceinline__ float bf2f(unsigned short u) {
  union { unsigned int i; float f; } c; c.i = ((unsigned int)u) << 16; return c.f;
}
__device__ __forceinline__ unsigned short f2bf(float f) {
  union { float f; unsigned int i; } c; c.f = f;
  unsigned int x = c.i;
  unsigned int lsb = (x >> 16) & 1u;
  x += 0x7fffu + lsb;
  return (unsigned short)(x >> 16);
}

// ---------- runtime dtype detection ----------
__global__ void k_detect(const void* x, const void* ei, int* modes) {
  __shared__ int cnt[2];
  int t = threadIdx.x;
  if (t < 2) cnt[t] = 0;
  __syncthreads();
  if (t < 64) {
    unsigned short u = ((const unsigned short*)x)[2 * t];
    unsigned e = (u >> 7) & 0xFFu;
    bool sane = (u == 0) || (e >= 96u && e <= 136u);
    if (!sane) atomicAdd(&cnt[0], 1);
  } else if (t < 192) {
    int i = t - 64;
    int v = ((const int*)ei)[2 * i + 1];
    if (v != 0) atomicAdd(&cnt[1], 1);
  }
  __syncthreads();
  if (t == 0) { modes[0] = (cnt[0] == 0) ? 1 : 0; modes[1] = (cnt[1] == 0) ? 1 : 0; }
}

// ---------- weight prep: permute to MFMA-B fragment layout (bf16) + fp32 biases ----
__global__ void k_prep(const void* ew, const void* eb, const void* w0, const void* b0,
                       const void* w1, const void* b1, const void* lw, const void* lb,
                       const int* __restrict__ modes,
                       unsigned short* __restrict__ BpE, unsigned short* __restrict__ BpW0,
                       unsigned short* __restrict__ BpW1, unsigned short* __restrict__ BpL,
                       float* __restrict__ biasF) {
  int tid = blockIdx.x * blockDim.x + threadIdx.x;
  const int m = modes[0];
  auto ldb = [&](const void* p, int idx) -> unsigned short {
    return m ? ((const unsigned short*)p)[idx] : f2bf(((const float*)p)[idx]);
  };
  auto ldf = [&](const void* p, int idx) -> float {
    return m ? bf2f(((const unsigned short*)p)[idx]) : ((const float*)p)[idx];
  };
  int e = tid;
  if (e < 40960) {
    int i = e & 7, l = (e >> 3) & 63, t = (e >> 9) & 7, ks = e >> 12;
    int k = ks * 32 + (l >> 4) * 8 + i, n = t * 16 + (l & 15);
    BpE[e] = (k < KIN) ? ldb(ew, k * 128 + n) : (unsigned short)0;
    return;
  }
  e -= 40960;
  if (e < 49152) {
    int i = e & 7, l = (e >> 3) & 63, t = (e >> 9) & 7, ks = (e >> 12) & 3, r = e >> 14;
    int k = ks * 32 + (l >> 4) * 8 + i, n = t * 16 + (l & 15);
    BpW0[e] = ldb(w0, r * 16384 + k * 128 + n);
    return;
  }
  e -= 49152;
  if (e < 49152) {
    int i = e & 7, l = (e >> 3) & 63, t = (e >> 9) & 7, ks = (e >> 12) & 3, r = e >> 14;
    int k = ks * 32 + (l >> 4) * 8 + i, n = t * 16 + (l & 15);
    BpW1[e] = ldb(w1, r * 16384 + k * 128 + n);
    return;
  }
  e -= 49152;
  if (e < 8192) {
    int i = e & 7, l = (e >> 3) & 63, t = (e >> 9) & 3, ks = e >> 11;
    int k = ks * 32 + (l >> 4) * 8 + i, n = t * 16 + (l & 15);
    BpL[e] = ldb(lw, k * 64 + n);
    return;
  }
  e -= 8192;
  if (e < 960) {
    float v;
    if (e < 128) v = ldf(eb, e);
    else if (e < 512) v = ldf(b0, e - 128);
    else if (e < 896) v = ldf(b1, e - 512);
    else v = ldf(lb, e - 896);
    biasF[e] = v;
  }
}

// ---------- pass 1: bucket-partition edges, packed (dst<<16)|src ----------
__global__ __launch_bounds__(256)
void k_part(const void* ei, const int* __restrict__ modes,
            unsigned int* __restrict__ bbuf, int* __restrict__ gcount, int E3, int E) {
  __shared__ int cnt[NB3];
  __shared__ int cur[NB3];
  const int tid = threadIdx.x;
  const int base = blockIdx.x * PCHUNK;
  for (int t = tid; t < NB3; t += 256) cnt[t] = 0;
  __syncthreads();
  const int m1 = modes[1];
  unsigned int pk[PCHUNK / 256];
#pragma unroll
  for (int j = 0; j < PCHUNK / 256; j++) {
    int i = base + tid + j * 256;
    pk[j] = 0xFFFFFFFFu;
    if (i < E3) {
      int r = (i >= E) + (i >= 2 * E);
      int e = i - r * E;
      long long jb = (long long)r * 2 * E;
      int s, d;
      if (m1) { const long long* p = (const long long*)ei; s = (int)p[jb + e]; d = (int)p[jb + E + e]; }
      else    { const int* p = (const int*)ei;             s = p[jb + e];      d = p[jb + E + e]; }
      pk[j] = ((unsigned int)d << 16) | (unsigned int)s;
      atomicAdd(&cnt[r * NBUCK + (d >> 10)], 1);
    }
  }
  __syncthreads();
  for (int t = tid; t < NB3; t += 256) cur[t] = atomicAdd(&gcount[t], cnt[t]);
  __syncthreads();
#pragma unroll
  for (int j = 0; j < PCHUNK / 256; j++) {
    if (pk[j] == 0xFFFFFFFFu) continue;
    int i = base + tid + j * 256;
    int r = (i >= E) + (i >= 2 * E);
    int bk = r * NBUCK + (int)(pk[j] >> 26);   // (dst>>10) = (pk>>16)>>10
    int pos = atomicAdd(&cur[bk], 1);
    if (pos < BCAP) bbuf[(long long)bk * BCAP + pos] = pk[j];
  }
}

// ---------- pass 2a: per-bucket LDS histogram -> deg, dis (coalesced, no atomics) ----
__global__ __launch_bounds__(512)
void k_bdeg(const unsigned int* __restrict__ bbuf, const int* __restrict__ gcount,
            int* __restrict__ deg, float* __restrict__ dis) {
  __shared__ int hist[TILE1K];
  const int b = blockIdx.x;
  const int r = b / NBUCK, nb = b - r * NBUCK;
  const int tid = threadIdx.x;
  for (int t = tid; t < TILE1K; t += 512) hist[t] = 0;
  __syncthreads();
  int n = gcount[b]; if (n > BCAP) n = BCAP;
  const unsigned int* bp = bbuf + (long long)b * BCAP;
  for (int i = tid; i < n; i += 512) {
    unsigned int u = bp[i];
    atomicAdd(&hist[(u >> 16) & 1023u], 1);
  }
  __syncthreads();
  for (int t = tid; t < TILE1K; t += 512) {
    int node = nb * TILE1K + t;
    if (node < NN) {
      int c = hist[t];
      deg[r * NN + node] = c;
      dis[r * NN + node] = rsqrtf((float)c + 1.0f);
    }
  }
}

// ---------- scan bucket counts -> tile offsets + total ----------
__global__ void k_scantiles(const int* __restrict__ tilesum, int* __restrict__ tileoff,
                            int* __restrict__ rp) {
  __shared__ int s[NB3];
  int t = threadIdx.x;
  if (t < NB3) s[t] = tilesum[t];
  __syncthreads();
  if (t == 0) {
    for (int r = 0; r < 3; r++) {
      int run = 0;
      for (int i = 0; i < NBUCK; i++) { int v = s[r * NBUCK + i]; s[r * NBUCK + i] = run; run += v; }
      rp[r * (NN + 1) + NN] = run;
    }
  }
  __syncthreads();
  if (t < NB3) tileoff[t] = s[t];
}

__global__ __launch_bounds__(256) void k_rowptr(const int* __restrict__ deg, const int* __restrict__ tileoff,
                                                int* __restrict__ rp) {
  int b = blockIdx.x;
  int r = b / NBUCK, tt = b - r * NBUCK;
  int tid = threadIdx.x;
  int base = tt * TILE1K + tid * 4;
  int v[4]; int tsum = 0;
#pragma unroll
  for (int j = 0; j < 4; j++) { int i = base + j; v[j] = (i < NN) ? deg[r * NN + i] : 0; tsum += v[j]; }
  int lane = tid & 63;
  int x = tsum;
  for (int off = 1; off < 64; off <<= 1) {
    int y = __shfl_up(x, off);
    if (lane >= off) x += y;
  }
  __shared__ int wsum[4];
  int wv = tid >> 6;
  if (lane == 63) wsum[wv] = x;
  __syncthreads();
  int run = tileoff[b] + (x - tsum);
  for (int k2 = 0; k2 < wv; k2++) run += wsum[k2];
#pragma unroll
  for (int j = 0; j < 4; j++) {
    int i = base + j;
    if (i < NN) rp[r * (NN + 1) + i] = run;
    run += v[j];
  }
}

// ---------- pass 2b: per-bucket scatter, cursor in LDS, writes XCD-local ----------
__global__ __launch_bounds__(512)
void k_scat2(const unsigned int* __restrict__ bbuf, const int* __restrict__ gcount,
             const int* __restrict__ rp, unsigned short* __restrict__ ssrc, int E) {
  __shared__ int cursor[TILE1K];
  const int b = blockIdx.x;
  const int r = b / NBUCK, nb = b - r * NBUCK;
  const int tid = threadIdx.x;
  for (int t = tid; t < TILE1K; t += 512) {
    int node = nb * TILE1K + t;
    cursor[t] = (node < NN) ? rp[r * (NN + 1) + node] : 0;
  }
  __syncthreads();
  int n = gcount[b]; if (n > BCAP) n = BCAP;
  const unsigned int* bp = bbuf + (long long)b * BCAP;
  unsigned short* sr = ssrc + (long long)r * E;
  for (int i = tid; i < n; i += 512) {
    unsigned int u = bp[i];
    int pos = atomicAdd(&cursor[(u >> 16) & 1023u], 1);
    sr[pos] = (unsigned short)(u & 0xFFFFu);
  }
}

// ---------- MFMA GEMM ----------
// OUTMODE: 0 = fp32 to Cout, 1 = fp16 to Cout, 2 = bf16 hi/lo split to Chi/Clo
template<int KSTEPS, int NTILES, int ASTR, bool AX, bool SPLIT, bool RELU, bool BIAS, int OUTMODE>
__global__ __launch_bounds__(256)
void k_mgemm(const void* __restrict__ Ahi_, const unsigned short* __restrict__ Alo,
             const unsigned short* __restrict__ Bp, const float* __restrict__ bias,
             void* __restrict__ Cout, unsigned short* __restrict__ Chi,
             unsigned short* __restrict__ Clo, int N, long long sBz, long long sCz,
             const int* __restrict__ modes) {
  int wave = threadIdx.x >> 6, lane = threadIdx.x & 63;
  int rowbase = blockIdx.x * 64 + wave * 16;
  if (rowbase >= NN) return;
  int z = blockIdx.z;
  int lr = lane & 15, lg = lane >> 4;
  const unsigned short* Bz = Bp + (long long)z * sBz;
  f32x4 acc[NTILES];
#pragma unroll
  for (int t = 0; t < NTILES; t++) acc[t] = (f32x4){0.f, 0.f, 0.f, 0.f};
  const unsigned short* ah = nullptr; const unsigned short* al = nullptr;
  int fmode = 1;
  if (!AX) {
    ah = (const unsigned short*)Ahi_ + (long long)(rowbase + lr) * ASTR + lg * 8;
    al = Alo + (long long)(rowbase + lr) * ASTR + lg * 8;
  } else {
    fmode = modes[0];
  }
#pragma unroll
  for (int ks = 0; ks < KSTEPS; ks++) {
    short8v a0, a1;
    if (AX) {
      union { unsigned int u[4]; short8v v; } tt;
      if (fmode) {
        const unsigned int* xu = (const unsigned int*)Ahi_;
        long long rb = (long long)(rowbase + lr) * (KIN / 2) + ks * 16 + lg * 4;
#pragma unroll
        for (int j = 0; j < 4; j++) {
          int kk = ks * 32 + lg * 8 + 2 * j;
          tt.u[j] = (kk < KIN) ? xu[rb + j] : 0u;
        }
      } else {
        const float* xf = (const float*)Ahi_;
        long long rb = (long long)(rowbase + lr) * KIN;
#pragma unroll
        for (int j = 0; j < 4; j++) {
          int kk = ks * 32 + lg * 8 + 2 * j;
          unsigned short lo_ = (kk < KIN) ? f2bf(xf[rb + kk]) : (unsigned short)0;
          unsigned short hi_ = (kk + 1 < KIN) ? f2bf(xf[rb + kk + 1]) : (unsigned short)0;
          tt.u[j] = (unsigned int)lo_ | ((unsigned int)hi_ << 16);
        }
      }
      a0 = tt.v;
    } else {
      a0 = *(const short8v*)(ah + ks * 32);
      if (SPLIT) a1 = *(const short8v*)(al + ks * 32);
    }
#pragma unroll
    for (int t = 0; t < NTILES; t++) {
      short8v b = *(const short8v*)(Bz + (((long long)ks * NTILES + t) * 64 + lane) * 8);
      acc[t] = __builtin_amdgcn_mfma_f32_16x16x32_bf16(a0, b, acc[t], 0, 0, 0);
      if (SPLIT) acc[t] = __builtin_amdgcn_mfma_f32_16x16x32_bf16(a1, b, acc[t], 0, 0, 0);
    }
  }
#pragma unroll
  for (int t = 0; t < NTILES; t++) {
    int col = t * 16 + lr;
    float bv = BIAS ? bias[col] : 0.f;
#pragma unroll
    for (int reg = 0; reg < 4; reg++) {
      int row = rowbase + lg * 4 + reg;
      float v = acc[t][reg] + bv;
      if (RELU) v = fmaxf(v, 0.f);
      if (OUTMODE == 2) {
        unsigned short h = f2bf(v);
        float resid = v - bf2f(h);
        Chi[(long long)row * N + col] = h;
        Clo[(long long)row * N + col] = f2bf(resid);
      } else if (OUTMODE == 1) {
        ((_Float16*)Cout)[(long long)z * sCz + (long long)row * N + col] = (_Float16)v;
      } else {
        ((float*)Cout)[(long long)z * sCz + (long long)row * N + col] = v;
      }
    }
  }
}

// ---------- per-node gather (fp16 HW, u16 ssrc) ----------
__global__ __launch_bounds__(256)
void k_gather(const _Float16* __restrict__ HW, const float* __restrict__ dis,
              const int* __restrict__ rp, const unsigned short* __restrict__ ssrc,
              const float* __restrict__ bias, unsigned short* __restrict__ Hhi,
              unsigned short* __restrict__ Hlo, int E) {
  int gw = (blockIdx.x * 256 + threadIdx.x) >> 6;   // one wave per node
  int lane = threadIdx.x & 63;
  if (gw >= NN) return;
  int c = lane * 2;
  float ax = 0.f, ay = 0.f;
#pragma unroll
  for (int r = 0; r < 3; r++) {
    const _Float16* HWr = HW + (long long)r * NN * HF;
    const float* disr = dis + r * NN;
    float di = disr[gw];
    f16x2 self = *(const f16x2*)(HWr + (long long)gw * HF + c);
    float2 bb = *(const float2*)(bias + r * HF + c);
    float d2 = di * di;
    ax += bb.x + (float)self.x * d2;
    ay += bb.y + (float)self.y * d2;
    int e = rp[r * (NN + 1) + gw];
    int end = rp[r * (NN + 1) + gw + 1];
    const unsigned short* sp = ssrc + (long long)r * E;
    for (; e + 4 <= end; e += 4) {
      int s0 = sp[e], s1 = sp[e + 1], s2 = sp[e + 2], s3 = sp[e + 3];
      float c0 = disr[s0] * di, c1 = disr[s1] * di, c2 = disr[s2] * di, c3 = disr[s3] * di;
      f16x2 v0 = *(const f16x2*)(HWr + (long long)s0 * HF + c);
      f16x2 v1 = *(const f16x2*)(HWr + (long long)s1 * HF + c);
      f16x2 v2 = *(const f16x2*)(HWr + (long long)s2 * HF + c);
      f16x2 v3 = *(const f16x2*)(HWr + (long long)s3 * HF + c);
      ax += (float)v0.x * c0 + (float)v1.x * c1 + (float)v2.x * c2 + (float)v3.x * c3;
      ay += (float)v0.y * c0 + (float)v1.y * c1 + (float)v2.y * c2 + (float)v3.y * c3;
    }
    for (; e < end; e++) {
      int s = sp[e];
      float cc = disr[s] * di;
      f16x2 v = *(const f16x2*)(HWr + (long long)s * HF + c);
      ax += (float)v.x * cc; ay += (float)v.y * cc;
    }
  }
  float vx = fmaxf(ax, 0.f), vy = fmaxf(ay, 0.f);
  ushort2 hi2, lo2;
  hi2.x = f2bf(vx); lo2.x = f2bf(vx - bf2f(hi2.x));
  hi2.y = f2bf(vy); lo2.y = f2bf(vy - bf2f(hi2.y));
  long long o = (long long)gw * HF + c;
  *(ushort2*)(Hhi + o) = hi2;
  *(ushort2*)(Hlo + o) = lo2;
}

extern "C" void kernel_launch(void* const* d_in, const int* in_sizes, int n_in,
                              void* d_out, int out_size, void* d_ws, size_t ws_size,
                              hipStream_t stream) {
  const void* x  = d_in[0];
  const void* ei = d_in[1];
  const void* ew = d_in[2];
  const void* eb = d_in[3];
  const void* w0 = d_in[4];
  const void* b0 = d_in[5];
  const void* w1 = d_in[6];
  const void* b1 = d_in[7];
  const void* lw = d_in[8];
  const void* lb = d_in[9];
  const int E = in_sizes[1] / 6;   // 800000
  const int E3 = 3 * E;

  char* w = (char*)d_ws;
  auto alloc = [&](size_t bytes) -> char* {
    char* p = w; w += (bytes + 255) & ~(size_t)255; return p;
  };
  unsigned short* Hhi = (unsigned short*)alloc((size_t)NN * HF * 2);
  unsigned short* Hlo = (unsigned short*)alloc((size_t)NN * HF * 2);
  _Float16* HWh       = (_Float16*)alloc((size_t)3 * NN * HF * 2);
  unsigned int* bbuf  = (unsigned int*)alloc((size_t)NB3 * BCAP * 4);
  unsigned short* BpE = (unsigned short*)alloc(40960 * 2);
  unsigned short* BpW0= (unsigned short*)alloc(49152 * 2);
  unsigned short* BpW1= (unsigned short*)alloc(49152 * 2);
  unsigned short* BpL = (unsigned short*)alloc(8192 * 2);
  float* biasF        = (float*)alloc(960 * 4);
  int*   gcount = (int*)alloc((size_t)NB3 * 4);
  int*   deg    = (int*)alloc((size_t)3 * NN * 4);
  float* dis    = (float*)alloc((size_t)3 * NN * 4);
  int*   rp     = (int*)alloc((size_t)3 * (NN + 1) * 4);
  int*   tileoff= (int*)alloc((size_t)NB3 * 4);
  unsigned short* ssrc = (unsigned short*)alloc((size_t)E3 * 2);
  int*   modes  = (int*)alloc(256);

  k_detect<<<1, 256, 0, stream>>>(x, ei, modes);
  hipMemsetAsync(gcount, 0, (size_t)NB3 * 4, stream);
  k_prep<<<(148416 + 255) / 256, 256, 0, stream>>>(ew, eb, w0, b0, w1, b1, lw, lb,
                                                   modes, BpE, BpW0, BpW1, BpL, biasF);
  k_part<<<(E3 + PCHUNK - 1) / PCHUNK, 256, 0, stream>>>(ei, modes, bbuf, gcount, E3, E);
  k_bdeg<<<NB3, 512, 0, stream>>>(bbuf, gcount, deg, dis);
  k_scantiles<<<1, 256, 0, stream>>>(gcount, tileoff, rp);
  k_rowptr<<<NB3, 256, 0, stream>>>(deg, tileoff, rp);
  k_scat2<<<NB3, 512, 0, stream>>>(bbuf, gcount, rp, ssrc, E);

  const int gm = (NN + 63) / 64;  // 782
  // embed: Hhi/Hlo = split(relu(x @ embW + embB)); A = x read directly (K pad->320)
  k_mgemm<10, 8, 0, true, false, true, true, 2>
      <<<dim3(gm, 1, 1), 256, 0, stream>>>(x, nullptr, BpE, biasF, nullptr, Hhi, Hlo,
                                           128, 0, 0, modes);
  // two GCN layers
  for (int layer = 0; layer < 2; layer++) {
    const unsigned short* Bp = layer == 0 ? BpW0 : BpW1;
    const float* bB = biasF + (layer == 0 ? 128 : 512);
    k_mgemm<4, 8, 128, false, true, false, false, 1>
        <<<dim3(gm, 1, 3), 256, 0, stream>>>(Hhi, Hlo, Bp, nullptr, HWh, nullptr, nullptr,
                                             128, 16384, (long long)NN * 128, modes);
    k_gather<<<(NN + 3) / 4, 256, 0, stream>>>(HWh, dis, rp, ssrc, bB, Hhi, Hlo, E);
  }
  // final: out = H @ lin + linB -> fp32
  k_mgemm<4, 4, 128, false, true, false, true, 0>
      <<<dim3(gm, 1, 1), 256, 0, stream>>>(Hhi, Hlo, BpL, biasF + 896, d_out,
                                           nullptr, nullptr, 64, 0, 0, modes);
}